// Round 8
// baseline (41.013 us; speedup 1.0000x reference)
//
#include <hip/hip_runtime.h>
#include <stdint.h>
#include <algorithm>
#include <numeric>

#define V_N    4096
#define B_N    4
#define C_N    128
#define POOL_N 1024   // V_N / POOLING_RATE
#define K_NBR  4

// ---------------- Threefry-2x32 (20 rounds), exactly as JAX lowers it ----
// Host-only: the permutation is input-independent, computed on CPU each
// call (deterministic), and shipped as a 2 KB kernarg struct.
static inline void tf2x32(uint32_t k0, uint32_t k1, uint32_t x0, uint32_t x1,
                          uint32_t& o0, uint32_t& o1) {
  uint32_t ks[3] = {k0, k1, k0 ^ k1 ^ 0x1BD11BDAu};
  const int R[5][4] = {{13,15,26,6},{17,29,16,24},{13,15,26,6},{17,29,16,24},{13,15,26,6}};
  x0 += ks[0]; x1 += ks[1];
  for (int g = 0; g < 5; ++g) {
    for (int r = 0; r < 4; ++r) {
      x0 += x1;
      const int rot = R[g][r];
      x1 = (x1 << rot) | (x1 >> (32 - rot));
      x1 ^= x0;
    }
    x0 += ks[(g + 1) % 3];
    x1 += ks[(g + 2) % 3] + (uint32_t)(g + 1);
  }
  o0 = x0; o1 = x1;
}

struct SampleIdx { unsigned short v[POOL_N]; };   // 2048 B kernarg payload

__device__ __forceinline__ bool lexlt(float d1, int i1, float d2, int i2) {
  return d1 < d2 || (d1 == d2 && i1 < i2);
}
__device__ __forceinline__ void ce(float& da, int& ia, float& db, int& ib) {
  if (!lexlt(da, ia, db, ib)) {
    float td = da; da = db; db = td;
    int   ti = ia; ia = ib; ib = ti;
  }
}

// ---------------- Fused kernel: kNN (per wave) + vgather + feature pool ---
// Block (g, b): 8 queries (one per wave).  Phase 1 = exact kNN (byte-identical
// logic to the validated round-7 kernel: same fp32 rounding, same lexicographic
// (dist, idx) selection => bit-exact).  Neighbor int4s parked in LDS; a single
// __syncthreads(); Phase 2 = all 512 threads gather-max fm directly from
// global for the block's 8 pooled outputs across all 128 channels.
__global__ __launch_bounds__(512) void fused_kernel(const float* __restrict__ verts,
                                                    const float* __restrict__ fm,
                                                    const SampleIdx si,
                                                    float* __restrict__ out) {
  __shared__ float4 sv4[V_N * 3 / 4];           // 48 KB packed xyz
  __shared__ int4 snbr[8];                      // per-wave top-4 neighbors
  const float* sv = (const float*)sv4;
  const int tid = threadIdx.x;
  const int b = blockIdx.y;
  const float4* vb4 = (const float4*)(verts + (size_t)b * V_N * 3);
#pragma unroll
  for (int w = 0; w < 6; ++w)
    sv4[tid + 512 * w] = vb4[tid + 512 * w];
  __syncthreads();

  const int lane = tid & 63;
  const int wv   = tid >> 6;                    // wave id 0..7 = query slot
  const int qid  = blockIdx.x * 8 + wv;         // 0..1023 output slot
  const int qv   = si.v[qid];                   // sampled vertex (kernarg)
  const float qx = sv[3 * qv], qy = sv[3 * qv + 1], qz = sv[3 * qv + 2];
  const float qq = __fadd_rn(__fadd_rn(__fmul_rn(qx, qx), __fmul_rn(qy, qy)),
                             __fmul_rn(qz, qz));

  float bd0 = 1e30f, bd1 = 1e30f, bd2 = 1e30f, bd3 = 1e30f;
  int   bi0 = -1, bi1 = -1, bi2 = -1, bi3 = -1;

#define EVAL(X, Y, Z, MC)                                                     \
  do {                                                                        \
    const float x_ = (X), y_ = (Y), z_ = (Z);                                 \
    const int mc_ = (MC);                                                     \
    const float qm_ = __fadd_rn(__fadd_rn(__fmul_rn(x_, x_),                  \
                                          __fmul_rn(y_, y_)),                 \
                                __fmul_rn(z_, z_));                           \
    const float in_ = __fmaf_rn(qz, z_, __fmaf_rn(qy, y_, __fmul_rn(qx, x_)));\
    const float dist = __fadd_rn(__fmaf_rn(-2.0f, in_, qm_), qq);             \
    if (mc_ != qv && dist < bd3) {                                            \
      if (dist < bd2) {                                                       \
        bd3 = bd2; bi3 = bi2;                                                 \
        if (dist < bd1) {                                                     \
          bd2 = bd1; bi2 = bi1;                                               \
          if (dist < bd0) { bd1 = bd0; bi1 = bi0; bd0 = dist; bi0 = mc_; }    \
          else            { bd1 = dist; bi1 = mc_; }                          \
        } else { bd2 = dist; bi2 = mc_; }                                     \
      } else { bd3 = dist; bi3 = mc_; }                                       \
    }                                                                         \
  } while (0)

#pragma unroll 4
  for (int i = 0; i < 16; ++i) {
    const int base = lane + 64 * i;             // 4 candidates per lane-iter
    const float4 c0 = sv4[3 * base + 0];
    const float4 c1 = sv4[3 * base + 1];
    const float4 c2 = sv4[3 * base + 2];
    const int m0 = 4 * base;
    EVAL(c0.x, c0.y, c0.z, m0 + 0);
    EVAL(c0.w, c1.x, c1.y, m0 + 1);
    EVAL(c1.z, c1.w, c2.x, m0 + 2);
    EVAL(c2.y, c2.z, c2.w, m0 + 3);
  }
#undef EVAL

  // 6-stage butterfly: merge two sorted 4-lists -> sorted top-4 (bitonic).
#pragma unroll
  for (int off = 1; off <= 32; off <<= 1) {
    const float e0 = __shfl_xor(bd0, off), e1 = __shfl_xor(bd1, off);
    const float e2 = __shfl_xor(bd2, off), e3 = __shfl_xor(bd3, off);
    const int   f0 = __shfl_xor(bi0, off), f1 = __shfl_xor(bi1, off);
    const int   f2 = __shfl_xor(bi2, off), f3 = __shfl_xor(bi3, off);
    const bool c0 = lexlt(bd0, bi0, e3, f3); bd0 = c0 ? bd0 : e3; bi0 = c0 ? bi0 : f3;
    const bool c1 = lexlt(bd1, bi1, e2, f2); bd1 = c1 ? bd1 : e2; bi1 = c1 ? bi1 : f2;
    const bool c2 = lexlt(bd2, bi2, e1, f1); bd2 = c2 ? bd2 : e1; bi2 = c2 ? bi2 : f1;
    const bool c3 = lexlt(bd3, bi3, e0, f0); bd3 = c3 ? bd3 : e0; bi3 = c3 ? bi3 : f0;
    ce(bd0, bi0, bd2, bi2); ce(bd1, bi1, bd3, bi3);
    ce(bd0, bi0, bd1, bi1); ce(bd2, bi2, bd3, bi3);
  }

  if (lane == 0) {
    snbr[wv] = make_int4(bi0, bi1, bi2, bi3);
    float* ov = out + ((size_t)b * POOL_N + qid) * 3;   // fused vertices_pool
    ov[0] = qx; ov[1] = qy; ov[2] = qz;
  }
  __syncthreads();

  // ---- Phase 2: feature max-pool for this block's 8 queries, all 128 ch --
  const float* fmb = fm + (size_t)b * C_N * V_N * 3;
  float* outF = out + (size_t)B_N * POOL_N * 3 + (size_t)b * C_N * POOL_N * 3;
  const int j0 = blockIdx.x * 8;
#pragma unroll
  for (int p = 0; p < 2; ++p) {
    const int o  = p * 512 + tid;               // 0..1023
    const int c  = o >> 3;                      // channel 0..127
    const int j8 = o & 7;                       // query within block
    const int4 nb = snbr[j8];
    const float* base = fmb + (size_t)c * V_N * 3;
    const float* p0 = base + nb.x * 3;
    const float* p1 = base + nb.y * 3;
    const float* p2 = base + nb.z * 3;
    const float* p3 = base + nb.w * 3;
    const float r0 = fmaxf(fmaxf(p0[0], p1[0]), fmaxf(p2[0], p3[0]));
    const float r1 = fmaxf(fmaxf(p0[1], p1[1]), fmaxf(p2[1], p3[1]));
    const float r2 = fmaxf(fmaxf(p0[2], p1[2]), fmaxf(p2[2], p3[2]));
    float* dst = outF + ((size_t)c * POOL_N + j0 + j8) * 3;
    dst[0] = r0; dst[1] = r1; dst[2] = r2;
  }
}

extern "C" void kernel_launch(void* const* d_in, const int* in_sizes, int n_in,
                              void* d_out, int out_size, void* d_ws, size_t ws_size,
                              hipStream_t stream) {
  const float* verts = (const float*)d_in[0];   // (4, 4096, 3) f32
  const float* fm    = (const float*)d_in[1];   // (4, 128, 4096, 3) f32
  float* out = (float*)d_out;                   // 12288 + 1572864 f32
  (void)d_ws; (void)ws_size;

  // ---- Host-side permutation (input-independent, recomputed every call) ---
  // key(42) = (0, 42); 2 rounds of foldlike split -> random_bits -> stable
  // sort; identical rank semantics to the device version validated absmax=0.
  uint32_t k0 = 0u, k1 = 42u, sub0[2], sub1[2];
  for (int r = 0; r < 2; ++r) {
    uint32_t n0, n1, s0, s1;
    tf2x32(k0, k1, 0u, 0u, n0, n1);
    tf2x32(k0, k1, 0u, 1u, s0, s1);
    sub0[r] = s0; sub1[r] = s1; k0 = n0; k1 = n1;
  }
  static thread_local uint32_t b1[V_N], b2[V_N];
  static thread_local int ord1[V_N], ord2[V_N];
  for (int i = 0; i < V_N; ++i) {
    uint32_t h, l;
    tf2x32(sub0[0], sub1[0], 0u, (uint32_t)i, h, l); b1[i] = h ^ l;
    tf2x32(sub0[1], sub1[1], 0u, (uint32_t)i, h, l); b2[i] = h ^ l;
  }
  std::iota(ord1, ord1 + V_N, 0);
  std::stable_sort(ord1, ord1 + V_N, [](int a, int b_) { return b1[a] < b1[b_]; });
  std::iota(ord2, ord2 + V_N, 0);
  std::stable_sort(ord2, ord2 + V_N, [](int a, int b_) { return b2[a] < b2[b_]; });
  SampleIdx si;
  for (int j = 0; j < POOL_N; ++j)
    si.v[j] = (unsigned short)ord1[ord2[j]];    // perm[j] = v1[ord2[j]]

  fused_kernel<<<dim3(POOL_N / 8, B_N), 512, 0, stream>>>(verts, fm, si, out);
}